// Round 3
// baseline (702.296 us; speedup 1.0000x reference)
//
#include <hip/hip_runtime.h>

// Multigrid V-cycle: div(c grad u) - u = rhs, 5-pt stencil, fp32, mask==1.
// Register-strip design: block = 256 threads = 64 cols x 4 strips of 16 rows
// covering a 64x64 region (TT = 64-2H output). Only u is exchanged via LDS;
// cx,cy (prescaled by pow2 inv_dx2 - bit-exact), rhs, omega/diag live in regs.
// OOB loads are zero => relaxation of zero stays zero => no bounds checks in
// sweeps (ring validity: depth>=s exact after s sweeps).

namespace {

constexpr float OMEGA_C = 0.9f;
constexpr int   SROW    = 66;   // LDS row stride: 64 + 2 pad cols (zeroed)

template<int STEPS, bool U0, bool RESTRICT, bool PROLONG>
__global__ __launch_bounds__(256, 4) void mg_fused(
    const float* __restrict__ uin, float* __restrict__ uout,
    const float* __restrict__ rhs,
    const float* __restrict__ cx, const float* __restrict__ cy,
    float inv_dx2, int n,
    const float* __restrict__ e,   // PROLONG: coarse error (n/2)^2
    float* __restrict__ rc)        // RESTRICT: coarse residual out (n/2)^2
{
    constexpr int H  = STEPS + (RESTRICT ? 1 : 0);
    constexpr int TT = 64 - 2 * H;
    static_assert(TT > 0 && (!RESTRICT || (TT % 2 == 0)), "geometry");

    __shared__ float su[SROW * 64];

    const int tid = threadIdx.x;
    const int tx  = tid & 63;
    const int ty  = tid >> 6;
    const int jb  = ty * 16;
    const int bx  = blockIdx.x * TT - H;
    const int by  = blockIdx.y * TT - H;
    const int gi  = bx + tx;
    const bool gi_ok = (unsigned)gi < (unsigned)n;
    const int nc = n >> 1;

    float u[16], rh[16], sv[16], cxs[16], cxw[16], cyn[16];
    float cys0;

    // zero pad columns (col 0 and col 65 of each LDS row)
    if (tid < 64) {
        su[tid * SROW]      = 0.0f;
        su[tid * SROW + 65] = 0.0f;
    }

    // ---- global loads: per-thread column strip (rows jb..jb+15, col tx) ----
    {
        const int gj0 = by + jb;
        {
            const int gjm = gj0 - 1;
            const bool okm = gi_ok && ((unsigned)gjm < (unsigned)n);
            cys0 = okm ? cy[(long)gjm * n + gi] * inv_dx2 : 0.0f;
        }
#pragma unroll
        for (int k = 0; k < 16; ++k) {
            const int gj = gj0 + k;
            const bool ok = gi_ok && ((unsigned)gj < (unsigned)n);
            float vcx = 0.f, vcxw = 0.f, vcy = 0.f, vrh = 0.f, vu = 0.f;
            if (ok) {
                const long g = (long)gj * n + gi;
                vcx = cx[g] * inv_dx2;                    // pow2 scale: exact
                if (gi > 0) vcxw = cx[g - 1] * inv_dx2;
                vcy = cy[g] * inv_dx2;
                vrh = rhs[g];
                if constexpr (!U0) vu = uin[g];
                if constexpr (PROLONG) {
                    const int ic = gi >> 1, jc = gj >> 1;
                    const int ii = ic + ((gi & 1) ? 1 : -1);
                    const int jj = jc + ((gj & 1) ? 1 : -1);
                    const bool iok = (unsigned)ii < (unsigned)nc;
                    const bool jok = (unsigned)jj < (unsigned)nc;
                    const float vc  = e[jc * nc + ic];
                    const float vsi = iok ? e[jc * nc + ii] : 0.0f;
                    const float vsj = jok ? e[jj * nc + ic] : 0.0f;
                    const float vd  = (iok && jok) ? e[jj * nc + ii] : 0.0f;
                    const float ws  = ((9.0f * vc + 3.0f * vsi) + 3.0f * vsj) + vd;
                    const float dn  = ((9.0f + (iok ? 3.0f : 0.0f)) + (jok ? 3.0f : 0.0f))
                                    + ((iok && jok) ? 1.0f : 0.0f);
                    vu += ws / dn;
                }
            }
            cxs[k] = vcx; cxw[k] = vcxw; cyn[k] = vcy; rh[k] = vrh; u[k] = vu;
        }
    }

    // ---- omega/diag, hoisted across sweeps (division done ONCE) ----
#pragma unroll
    for (int k = 0; k < 16; ++k) {
        const float cys  = k ? cyn[k - 1] : cys0;
        const float diag = -((cxs[k] + cxw[k]) + (cyn[k] + cys)) - 1.0f;  // LAM=1
        const float inv  = (diag != 0.0f) ? 1.0f / diag : 0.0f;
        sv[k] = OMEGA_C * inv;   // (OMEGA*inv)*r matches ref associativity
    }

    // ---- write u strip to LDS ----
    {
        const int base = jb * SROW + 1 + tx;
#pragma unroll
        for (int k = 0; k < 16; ++k) su[base + k * SROW] = u[k];
    }
    __syncthreads();

    // ---- fused Jacobi sweeps (validity ring shrinks 1/sweep) ----
    for (int s = 0; s < STEPS; ++s) {
        const float us_edge = (jb > 0)       ? su[(jb - 1)  * SROW + 1 + tx] : 0.0f;
        const float un_edge = (jb + 16 < 64) ? su[(jb + 16) * SROW + 1 + tx] : 0.0f;
        float prev_old = us_edge;
#pragma unroll
        for (int k = 0; k < 16; ++k) {
            const int rbase = (jb + k) * SROW + 1 + tx;
            const float um = u[k];
            const float ue = su[rbase + 1];    // pad col -> 0 at tx=63
            const float uw = su[rbase - 1];    // pad col -> 0 at tx=0
            const float un = (k < 15) ? u[k + 1] : un_edge;
            const float us = prev_old;
            const float cys = k ? cyn[k - 1] : cys0;
            const float lx = cxs[k] * (ue - um) - cxw[k] * (um - uw);
            const float ly = cyn[k] * (un - um) - cys    * (um - us);
            const float r  = rh[k] - ((lx + ly) - um);
            prev_old = um;
            u[k] = um + sv[k] * r;
        }
        __syncthreads();
        if (!RESTRICT && s == STEPS - 1) break;   // last write-back not needed
        {
            const int base = jb * SROW + 1 + tx;
#pragma unroll
            for (int k = 0; k < 16; ++k) su[base + k * SROW] = u[k];
        }
        __syncthreads();
    }

    // ---- store smoothed tile (depth >= H fully valid) ----
#pragma unroll
    for (int k = 0; k < 16; ++k) {
        const int lr = jb + k;
        if (lr >= H && lr < H + TT && tx >= H && tx < H + TT) {
            const int gj = by + lr;
            if (gj < n && gi < n) uout[(long)gj * n + gi] = u[k];
        }
    }

    // ---- fused residual + full-weighting restriction ----
    if constexpr (RESTRICT) {
        float res[16];
        const float us_edge = (jb > 0)       ? su[(jb - 1)  * SROW + 1 + tx] : 0.0f;
        const float un_edge = (jb + 16 < 64) ? su[(jb + 16) * SROW + 1 + tx] : 0.0f;
        float prev_old = us_edge;
#pragma unroll
        for (int k = 0; k < 16; ++k) {
            const int rbase = (jb + k) * SROW + 1 + tx;
            const float um = u[k];
            const float ue = su[rbase + 1];
            const float uw = su[rbase - 1];
            const float un = (k < 15) ? u[k + 1] : un_edge;
            const float us = prev_old;
            const float cys = k ? cyn[k - 1] : cys0;
            const float lx = cxs[k] * (ue - um) - cxw[k] * (um - uw);
            const float ly = cyn[k] * (un - um) - cys    * (um - us);
            res[k] = rh[k] - ((lx + ly) - um);
            prev_old = um;
        }
        __syncthreads();
        {
            const int base = jb * SROW + 1 + tx;
#pragma unroll
            for (int k = 0; k < 16; ++k) su[base + k * SROW] = res[k];
        }
        __syncthreads();

        constexpr int TC = TT / 2;   // 29
        for (int t = tid; t < 1024; t += 256) {
            const int tj = t >> 5, ti = t & 31;
            if (tj < TC && ti < TC) {
                const int a = (H + 2 * tj) * SROW + 1 + (H + 2 * ti);
                // ref order: ((even,even)+(odd,even))+(even,odd))+(odd,odd); /4 exact
                const float sum = ((su[a] + su[a + SROW]) + su[a + 1]) + su[a + SROW + 1];
                const int gjc = blockIdx.y * TC + tj;
                const int gic = blockIdx.x * TC + ti;
                if (gjc < nc && gic < nc) rc[gjc * nc + gic] = sum * 0.25f;
            }
        }
    }
}

dim3 grd(int n, int tt) { int g = (n + tt - 1) / tt; return dim3(g, g); }

} // namespace

extern "C" void kernel_launch(void* const* d_in, const int* in_sizes, int n_in,
                              void* d_out, int out_size, void* d_ws, size_t ws_size,
                              hipStream_t stream) {
    (void)in_sizes; (void)n_in; (void)out_size; (void)ws_size;

    const float* cx0 = (const float*)d_in[1];
    const float* cy0 = (const float*)d_in[2];
    const float* cx1 = (const float*)d_in[4];
    const float* cy1 = (const float*)d_in[5];
    const float* cx2 = (const float*)d_in[7];
    const float* cy2 = (const float*)d_in[8];
    const float* cx3 = (const float*)d_in[10];
    const float* cy3 = (const float*)d_in[11];
    const float* rhs = (const float*)d_in[12];

    float* O = (float*)d_out;            // 2048^2
    float* w = (float*)d_ws;
    float* W   = w; w += 2048 * 2048;    // fine pre-smoothed u
    float* rc1 = w; w += 1024 * 1024;
    float* a1  = w; w += 1024 * 1024;
    float* b1  = w; w += 1024 * 1024;
    float* rc2 = w; w += 512 * 512;
    float* a2  = w; w += 512 * 512;
    float* b2  = w; w += 512 * 512;
    float* rc3 = w; w += 256 * 256;
    float* a3  = w; w += 256 * 256;
    float* b3  = w; w += 256 * 256;

    const dim3 blk(256, 1, 1);
    // TT: STEPS=2+RESTRICT -> 58; STEPS=2 (prolong) -> 60; STEPS=11 -> 42.

    for (int c = 0; c < 2; ++c) {
        if (c == 0)
            mg_fused<2, true,  true, false><<<grd(2048, 58), blk, 0, stream>>>(
                nullptr, W, rhs, cx0, cy0, 1.0f, 2048, nullptr, rc1);
        else
            mg_fused<2, false, true, false><<<grd(2048, 58), blk, 0, stream>>>(
                O, W, rhs, cx0, cy0, 1.0f, 2048, nullptr, rc1);
        mg_fused<2, true, true, false><<<grd(1024, 58), blk, 0, stream>>>(
            nullptr, a1, rc1, cx1, cy1, 0.25f, 1024, nullptr, rc2);
        mg_fused<2, true, true, false><<<grd(512, 58), blk, 0, stream>>>(
            nullptr, a2, rc2, cx2, cy2, 0.0625f, 512, nullptr, rc3);
        // coarsest: 2 + 20 = 22 consecutive sweeps = 11 + 11
        mg_fused<11, true,  false, false><<<grd(256, 42), blk, 0, stream>>>(
            nullptr, a3, rc3, cx3, cy3, 0.015625f, 256, nullptr, nullptr);
        mg_fused<11, false, false, false><<<grd(256, 42), blk, 0, stream>>>(
            a3, b3, rc3, cx3, cy3, 0.015625f, 256, nullptr, nullptr);
        // prolong-add + post-smooth(2)
        mg_fused<2, false, false, true><<<grd(512, 60), blk, 0, stream>>>(
            a2, b2, rc2, cx2, cy2, 0.0625f, 512, b3, nullptr);
        mg_fused<2, false, false, true><<<grd(1024, 60), blk, 0, stream>>>(
            a1, b1, rc1, cx1, cy1, 0.25f, 1024, b2, nullptr);
        mg_fused<2, false, false, true><<<grd(2048, 60), blk, 0, stream>>>(
            W, O, rhs, cx0, cy0, 1.0f, 2048, b1, nullptr);
    }
}

// Round 4
// 350.847 us; speedup vs baseline: 2.0017x; 2.0017x over previous
//
#include <hip/hip_runtime.h>

// Multigrid V-cycle: div(c grad u) - u = rhs, 5-pt stencil, fp32, mask==1.
// Register-strip design, generic region:
//   block BLK threads = RG cols x (BLK/RG) strips of SR=RG*RG/BLK rows,
//   covering an RG x RG region; output tile TT = RG-2H, H = fused halo.
// Only u lives in LDS; cx,cy (prescaled by pow2 inv_dx2 - bit-exact), rhs,
// omega/diag (division hoisted, done once) live in registers.
// cxw comes from __shfl_up of cxs (lane tx=0 garbage-but-finite: depth-0 halo
// column is outside the validity ring; at domain edges shuffled val is the
// exact OOB zero). OOB loads are zero => relaxation stays finite => no bounds
// checks in sweeps (ring validity: depth>=s exact after s sweeps).
// Fine levels: RG=64/BLK=512/SR=8.  Coarsest: RG=32/BLK=256/SR=4 (676 blocks).

namespace {

constexpr float OMEGA_C = 0.9f;

template<int STEPS, int RG, int BLK, bool U0, bool RESTRICT, bool PROLONG>
__global__ __launch_bounds__(BLK) void mg_fused(
    const float* __restrict__ uin, float* __restrict__ uout,
    const float* __restrict__ rhs,
    const float* __restrict__ cx, const float* __restrict__ cy,
    float inv_dx2, int n,
    const float* __restrict__ e,   // PROLONG: coarse error (n/2)^2
    float* __restrict__ rc)        // RESTRICT: coarse residual out (n/2)^2
{
    constexpr int H    = STEPS + (RESTRICT ? 1 : 0);
    constexpr int TT   = RG - 2 * H;
    constexpr int NS   = BLK / RG;          // strips per region
    constexpr int SR   = RG / NS;           // rows per strip
    constexpr int SROW = RG + 2;            // LDS row stride (pad cols 0, RG+1)
    static_assert(TT > 0 && BLK % RG == 0 && RG % NS == 0, "geometry");
    static_assert(!RESTRICT || (TT % 2 == 0), "restrict needs even tile");

    __shared__ float su[RG * SROW];

    const int tid = threadIdx.x;
    const int tx  = tid & (RG - 1);
    const int ty  = tid / RG;
    const int jb  = ty * SR;
    const int bx  = blockIdx.x * TT - H;
    const int by  = blockIdx.y * TT - H;
    const int gi  = bx + tx;
    const bool gi_ok = (unsigned)gi < (unsigned)n;
    const int nc = n >> 1;

    float u[SR], rh[SR], sv[SR], cxs[SR], cxw[SR], cyn[SR];
    float cys0;

    // zero the pad columns
    if (tid < RG) {
        su[tid * SROW]          = 0.0f;
        su[tid * SROW + RG + 1] = 0.0f;
    }

    // ---- global loads: per-thread column strip (rows jb..jb+SR-1, col tx) ----
    {
        const int gj0 = by + jb;
        {
            const int gjm = gj0 - 1;
            const bool okm = gi_ok && ((unsigned)gjm < (unsigned)n);
            cys0 = okm ? cy[(long)gjm * n + gi] * inv_dx2 : 0.0f;
        }
#pragma unroll
        for (int k = 0; k < SR; ++k) {
            const int gj = gj0 + k;
            const bool ok = gi_ok && ((unsigned)gj < (unsigned)n);
            float vcx = 0.f, vcy = 0.f, vrh = 0.f, vu = 0.f;
            if (ok) {
                const long g = (long)gj * n + gi;
                vcx = cx[g] * inv_dx2;                    // pow2 scale: exact
                vcy = cy[g] * inv_dx2;
                vrh = rhs[g];
                if constexpr (!U0) vu = uin[g];
                if constexpr (PROLONG) {
                    const int ic = gi >> 1, jc = gj >> 1;
                    const int ii = ic + ((gi & 1) ? 1 : -1);
                    const int jj = jc + ((gj & 1) ? 1 : -1);
                    const bool iok = (unsigned)ii < (unsigned)nc;
                    const bool jok = (unsigned)jj < (unsigned)nc;
                    const float vc  = e[jc * nc + ic];
                    const float vsi = iok ? e[jc * nc + ii] : 0.0f;
                    const float vsj = jok ? e[jj * nc + ic] : 0.0f;
                    const float vd  = (iok && jok) ? e[jj * nc + ii] : 0.0f;
                    const float ws  = ((9.0f * vc + 3.0f * vsi) + 3.0f * vsj) + vd;
                    const float dn  = ((9.0f + (iok ? 3.0f : 0.0f)) + (jok ? 3.0f : 0.0f))
                                    + ((iok && jok) ? 1.0f : 0.0f);
                    vu += ws / dn;
                }
            }
            cxs[k] = vcx; cyn[k] = vcy; rh[k] = vrh; u[k] = vu;
        }
    }

    // ---- cxw from lane shuffle (no second cx stream, no bounds checks) ----
    // lane tx==0 keeps its own value: depth-0 column, outside validity ring.
#pragma unroll
    for (int k = 0; k < SR; ++k) cxw[k] = __shfl_up(cxs[k], 1, 64);

    // ---- omega/diag hoisted across sweeps (division done ONCE) ----
#pragma unroll
    for (int k = 0; k < SR; ++k) {
        const float cys  = k ? cyn[k - 1] : cys0;
        const float diag = -((cxs[k] + cxw[k]) + (cyn[k] + cys)) - 1.0f;  // LAM=1
        const float inv  = (diag != 0.0f) ? 1.0f / diag : 0.0f;
        sv[k] = OMEGA_C * inv;   // (OMEGA*inv)*r matches ref associativity
    }

    // ---- write u strip to LDS ----
    {
        const int base = jb * SROW + 1 + tx;
#pragma unroll
        for (int k = 0; k < SR; ++k) su[base + k * SROW] = u[k];
    }
    __syncthreads();

    // ---- fused Jacobi sweeps (validity ring shrinks 1/sweep) ----
    for (int s = 0; s < STEPS; ++s) {
        const float us_edge = (jb > 0)       ? su[(jb - 1)   * SROW + 1 + tx] : 0.0f;
        const float un_edge = (jb + SR < RG) ? su[(jb + SR)  * SROW + 1 + tx] : 0.0f;
        float prev_old = us_edge;
#pragma unroll
        for (int k = 0; k < SR; ++k) {
            const int rbase = (jb + k) * SROW + 1 + tx;
            const float um = u[k];
            const float ue = su[rbase + 1];    // pad col -> 0 at tx=RG-1
            const float uw = su[rbase - 1];    // pad col -> 0 at tx=0
            const float un = (k < SR - 1) ? u[k + 1] : un_edge;
            const float us = prev_old;
            const float cys = k ? cyn[k - 1] : cys0;
            const float lx = cxs[k] * (ue - um) - cxw[k] * (um - uw);
            const float ly = cyn[k] * (un - um) - cys    * (um - us);
            const float r  = rh[k] - ((lx + ly) - um);
            prev_old = um;
            u[k] = um + sv[k] * r;
        }
        __syncthreads();
        if (!RESTRICT && s == STEPS - 1) break;   // last write-back not needed
        {
            const int base = jb * SROW + 1 + tx;
#pragma unroll
            for (int k = 0; k < SR; ++k) su[base + k * SROW] = u[k];
        }
        __syncthreads();
    }

    // ---- store smoothed tile (depth >= H fully valid) ----
#pragma unroll
    for (int k = 0; k < SR; ++k) {
        const int lr = jb + k;
        if (lr >= H && lr < H + TT && tx >= H && tx < H + TT) {
            const int gj = by + lr;
            if (gj < n && gi < n) uout[(long)gj * n + gi] = u[k];
        }
    }

    // ---- fused residual + full-weighting restriction ----
    if constexpr (RESTRICT) {
        float res[SR];
        const float us_edge = (jb > 0)       ? su[(jb - 1)  * SROW + 1 + tx] : 0.0f;
        const float un_edge = (jb + SR < RG) ? su[(jb + SR) * SROW + 1 + tx] : 0.0f;
        float prev_old = us_edge;
#pragma unroll
        for (int k = 0; k < SR; ++k) {
            const int rbase = (jb + k) * SROW + 1 + tx;
            const float um = u[k];
            const float ue = su[rbase + 1];
            const float uw = su[rbase - 1];
            const float un = (k < SR - 1) ? u[k + 1] : un_edge;
            const float us = prev_old;
            const float cys = k ? cyn[k - 1] : cys0;
            const float lx = cxs[k] * (ue - um) - cxw[k] * (um - uw);
            const float ly = cyn[k] * (un - um) - cys    * (um - us);
            res[k] = rh[k] - ((lx + ly) - um);
            prev_old = um;
        }
        __syncthreads();
        {
            const int base = jb * SROW + 1 + tx;
#pragma unroll
            for (int k = 0; k < SR; ++k) su[base + k * SROW] = res[k];
        }
        __syncthreads();

        constexpr int TC = TT / 2;
        for (int t = tid; t < 1024; t += BLK) {
            const int tj = t >> 5, ti = t & 31;
            if (tj < TC && ti < TC) {
                const int a = (H + 2 * tj) * SROW + 1 + (H + 2 * ti);
                // ref order: ((ee+oe)+eo)+oo; count==4 -> *0.25 exact
                const float sum = ((su[a] + su[a + SROW]) + su[a + 1]) + su[a + SROW + 1];
                const int gjc = blockIdx.y * TC + tj;
                const int gic = blockIdx.x * TC + ti;
                if (gjc < nc && gic < nc) rc[gjc * nc + gic] = sum * 0.25f;
            }
        }
    }
}

static dim3 grd(int n, int tt) { int g = (n + tt - 1) / tt; return dim3(g, g); }

} // namespace

extern "C" void kernel_launch(void* const* d_in, const int* in_sizes, int n_in,
                              void* d_out, int out_size, void* d_ws, size_t ws_size,
                              hipStream_t stream) {
    (void)in_sizes; (void)n_in; (void)out_size; (void)ws_size;

    const float* cx0 = (const float*)d_in[1];
    const float* cy0 = (const float*)d_in[2];
    const float* cx1 = (const float*)d_in[4];
    const float* cy1 = (const float*)d_in[5];
    const float* cx2 = (const float*)d_in[7];
    const float* cy2 = (const float*)d_in[8];
    const float* cx3 = (const float*)d_in[10];
    const float* cy3 = (const float*)d_in[11];
    const float* rhs = (const float*)d_in[12];

    float* O = (float*)d_out;            // 2048^2
    float* w = (float*)d_ws;
    float* W   = w; w += 2048 * 2048;    // fine pre-smoothed u
    float* rc1 = w; w += 1024 * 1024;
    float* a1  = w; w += 1024 * 1024;
    float* b1  = w; w += 1024 * 1024;
    float* rc2 = w; w += 512 * 512;
    float* a2  = w; w += 512 * 512;
    float* b2  = w; w += 512 * 512;
    float* rc3 = w; w += 256 * 256;
    float* a3  = w; w += 256 * 256;
    float* b3  = w; w += 256 * 256;

    const dim3 b512(512, 1, 1), b256(256, 1, 1);
    // TT: STEPS=2+RESTRICT -> 58; STEPS=2+PROLONG -> 60; coarse RG=32,S=11 -> 10.

    for (int c = 0; c < 2; ++c) {
        if (c == 0)
            mg_fused<2, 64, 512, true,  true, false><<<grd(2048, 58), b512, 0, stream>>>(
                nullptr, W, rhs, cx0, cy0, 1.0f, 2048, nullptr, rc1);
        else
            mg_fused<2, 64, 512, false, true, false><<<grd(2048, 58), b512, 0, stream>>>(
                O, W, rhs, cx0, cy0, 1.0f, 2048, nullptr, rc1);
        mg_fused<2, 64, 512, true, true, false><<<grd(1024, 58), b512, 0, stream>>>(
            nullptr, a1, rc1, cx1, cy1, 0.25f, 1024, nullptr, rc2);
        mg_fused<2, 64, 512, true, true, false><<<grd(512, 58), b512, 0, stream>>>(
            nullptr, a2, rc2, cx2, cy2, 0.0625f, 512, nullptr, rc3);
        // coarsest: 22 consecutive sweeps = 11 + 11 (RG=32 -> 676 blocks each)
        mg_fused<11, 32, 256, true,  false, false><<<grd(256, 10), b256, 0, stream>>>(
            nullptr, a3, rc3, cx3, cy3, 0.015625f, 256, nullptr, nullptr);
        mg_fused<11, 32, 256, false, false, false><<<grd(256, 10), b256, 0, stream>>>(
            a3, b3, rc3, cx3, cy3, 0.015625f, 256, nullptr, nullptr);
        // prolong-add + post-smooth(2)
        mg_fused<2, 64, 512, false, false, true><<<grd(512, 60), b512, 0, stream>>>(
            a2, b2, rc2, cx2, cy2, 0.0625f, 512, b3, nullptr);
        mg_fused<2, 64, 512, false, false, true><<<grd(1024, 60), b512, 0, stream>>>(
            a1, b1, rc1, cx1, cy1, 0.25f, 1024, b2, nullptr);
        mg_fused<2, 64, 512, false, false, true><<<grd(2048, 60), b512, 0, stream>>>(
            W, O, rhs, cx0, cy0, 1.0f, 2048, b1, nullptr);
    }
}

// Round 7
// 336.077 us; speedup vs baseline: 2.0897x; 1.0439x over previous
//
#include <hip/hip_runtime.h>

// Multigrid V-cycle: div(c grad u) - u = rhs, 5-pt stencil, fp32, mask==1.
// Register-strip + double-buffered LDS (ONE barrier per sweep).
//   block BLK = RG cols x NS strips of SR rows covering RG x RG region;
//   output tile TT = RG-2H. Only u is exchanged via LDS (2 buffers);
//   cx,cy (prescaled by pow2 inv_dx2 - exact), rhs, omega/diag in registers.
// Schedule (13 dispatches):
//   c1: A0 A1 A2 C22 B2 B1 | X(=B0+A0'+restrict, 4 sweeps) | c2: A1 A2 C22 B2 B1 B0'
// L0 u ping-pong: A0->O, X: O->W, B0': W->O (final).

namespace {

constexpr float OMEGA_C = 0.9f;

template<int STEPS, int RG, int BLK, bool U0, bool RESTRICT, bool PROLONG>
__global__ __launch_bounds__(BLK) void mg_fused(
    const float* __restrict__ uin, float* __restrict__ uout,
    const float* __restrict__ rhs,
    const float* __restrict__ cx, const float* __restrict__ cy,
    float inv_dx2, int n,
    const float* __restrict__ e,   // PROLONG: coarse error (n/2)^2
    float* __restrict__ rc)        // RESTRICT: coarse residual out (n/2)^2
{
    constexpr int H    = STEPS + (RESTRICT ? 1 : 0);
    constexpr int TT   = RG - 2 * H;
    constexpr int NS   = BLK / RG;
    constexpr int SR   = RG / NS;
    constexpr int SROW = RG + 2;          // pad cols 0 and RG+1 (zeroed)
    static_assert(TT > 0 && BLK % RG == 0 && RG % NS == 0, "geometry");
    static_assert(!RESTRICT || (TT % 2 == 0), "restrict needs even tile");

    __shared__ float sA[RG * SROW];
    __shared__ float sB[RG * SROW];

    const int tid = threadIdx.x;
    const int tx  = tid & (RG - 1);
    const int ty  = tid / RG;
    const int jb  = ty * SR;
    const int bx  = blockIdx.x * TT - H;
    const int by  = blockIdx.y * TT - H;
    const int gi  = bx + tx;
    const bool gi_ok = (unsigned)gi < (unsigned)n;
    const int nc = n >> 1;

    float u[SR], rh[SR], sv[SR], cxs[SR], cxw[SR], cyn[SR];
    float cys0;

    // zero pad columns in both buffers
    if (tid < RG) {
        sA[tid * SROW] = 0.0f;  sA[tid * SROW + RG + 1] = 0.0f;
        sB[tid * SROW] = 0.0f;  sB[tid * SROW + RG + 1] = 0.0f;
    }

    // ---- global loads: per-thread column strip ----
    {
        const int gj0 = by + jb;
        {
            const int gjm = gj0 - 1;
            const bool okm = gi_ok && ((unsigned)gjm < (unsigned)n);
            cys0 = okm ? cy[(long)gjm * n + gi] * inv_dx2 : 0.0f;
        }
#pragma unroll
        for (int k = 0; k < SR; ++k) {
            const int gj = gj0 + k;
            const bool ok = gi_ok && ((unsigned)gj < (unsigned)n);
            float vcx = 0.f, vcy = 0.f, vrh = 0.f, vu = 0.f;
            if (ok) {
                const long g = (long)gj * n + gi;
                vcx = cx[g] * inv_dx2;                    // pow2 scale: exact
                vcy = cy[g] * inv_dx2;
                vrh = rhs[g];
                if constexpr (!U0) vu = uin[g];
                if constexpr (PROLONG) {
                    const int ic = gi >> 1, jc = gj >> 1;
                    const int ii = ic + ((gi & 1) ? 1 : -1);
                    const int jj = jc + ((gj & 1) ? 1 : -1);
                    const bool iok = (unsigned)ii < (unsigned)nc;
                    const bool jok = (unsigned)jj < (unsigned)nc;
                    const float vc  = e[jc * nc + ic];
                    const float vsi = iok ? e[jc * nc + ii] : 0.0f;
                    const float vsj = jok ? e[jj * nc + ic] : 0.0f;
                    const float vd  = (iok && jok) ? e[jj * nc + ii] : 0.0f;
                    const float ws  = ((9.0f * vc + 3.0f * vsi) + 3.0f * vsj) + vd;
                    const float dn  = ((9.0f + (iok ? 3.0f : 0.0f)) + (jok ? 3.0f : 0.0f))
                                    + ((iok && jok) ? 1.0f : 0.0f);
                    vu += ws / dn;
                }
            }
            cxs[k] = vcx; cyn[k] = vcy; rh[k] = vrh; u[k] = vu;
        }
    }

    // cxw via lane shuffle (lane tx==0: depth-0 column, outside validity ring)
#pragma unroll
    for (int k = 0; k < SR; ++k) cxw[k] = __shfl_up(cxs[k], 1, 64);

    // omega/diag hoisted (division ONCE)
#pragma unroll
    for (int k = 0; k < SR; ++k) {
        const float cys  = k ? cyn[k - 1] : cys0;
        const float diag = -((cxs[k] + cxw[k]) + (cyn[k] + cys)) - 1.0f;  // LAM=1
        const float inv  = (diag != 0.0f) ? 1.0f / diag : 0.0f;
        sv[k] = OMEGA_C * inv;
    }

    // seed buffer A with u
    {
        const int base = jb * SROW + 1 + tx;
#pragma unroll
        for (int k = 0; k < SR; ++k) sA[base + k * SROW] = u[k];
    }
    __syncthreads();

    // ---- fused sweeps, double-buffered: ONE barrier per sweep ----
    float* cur = sA;
    float* nxt = sB;
    for (int s = 0; s < STEPS; ++s) {
        const float us_edge = (jb > 0)       ? cur[(jb - 1)  * SROW + 1 + tx] : 0.0f;
        const float un_edge = (jb + SR < RG) ? cur[(jb + SR) * SROW + 1 + tx] : 0.0f;
        const int base = jb * SROW + 1 + tx;
        float prev_old = us_edge;
        const bool last = (s == STEPS - 1);
#pragma unroll
        for (int k = 0; k < SR; ++k) {
            const float um = u[k];
            const float ue = cur[base + k * SROW + 1];
            const float uw = cur[base + k * SROW - 1];
            const float un = (k < SR - 1) ? u[k + 1] : un_edge;
            const float us = prev_old;
            const float cys = k ? cyn[k - 1] : cys0;
            const float lx = cxs[k] * (ue - um) - cxw[k] * (um - uw);
            const float ly = cyn[k] * (un - um) - cys    * (um - us);
            const float r  = rh[k] - ((lx + ly) - um);
            prev_old = um;
            u[k] = um + sv[k] * r;
        }
        if (last && !RESTRICT) break;          // neighbors not needed again
#pragma unroll
        for (int k = 0; k < SR; ++k) nxt[base + k * SROW] = u[k];
        __syncthreads();
        float* t = cur; cur = nxt; nxt = t;
    }

    // ---- store smoothed tile (depth >= H fully valid) ----
#pragma unroll
    for (int k = 0; k < SR; ++k) {
        const int lr = jb + k;
        if (lr >= H && lr < H + TT && tx >= H && tx < H + TT) {
            const int gj = by + lr;
            if (gj < n && gi < n) uout[(long)gj * n + gi] = u[k];
        }
    }

    // ---- fused residual + full-weighting restriction ----
    if constexpr (RESTRICT) {
        // post-sweep u is in `cur` (last sweep wrote + swapped). Residual from it.
        float res[SR];
        const float us_edge = (jb > 0)       ? cur[(jb - 1)  * SROW + 1 + tx] : 0.0f;
        const float un_edge = (jb + SR < RG) ? cur[(jb + SR) * SROW + 1 + tx] : 0.0f;
        const int base = jb * SROW + 1 + tx;
        float prev_old = us_edge;
#pragma unroll
        for (int k = 0; k < SR; ++k) {
            const float um = u[k];
            const float ue = cur[base + k * SROW + 1];
            const float uw = cur[base + k * SROW - 1];
            const float un = (k < SR - 1) ? u[k + 1] : un_edge;
            const float us = prev_old;
            const float cys = k ? cyn[k - 1] : cys0;
            const float lx = cxs[k] * (ue - um) - cxw[k] * (um - uw);
            const float ly = cyn[k] * (un - um) - cys    * (um - us);
            res[k] = rh[k] - ((lx + ly) - um);
            prev_old = um;
        }
        __syncthreads();   // all reads of cur done before overwriting nxt
#pragma unroll
        for (int k = 0; k < SR; ++k) nxt[base + k * SROW] = res[k];
        __syncthreads();

        constexpr int TC = TT / 2;
        for (int t = tid; t < TC * TC; t += BLK) {
            const int tj = t / TC, ti = t - tj * TC;    // TC constexpr -> magic mul
            const int a = (H + 2 * tj) * SROW + 1 + (H + 2 * ti);
            const float sum = ((nxt[a] + nxt[a + SROW]) + nxt[a + 1]) + nxt[a + SROW + 1];
            const int gjc = blockIdx.y * TC + tj;
            const int gic = blockIdx.x * TC + ti;
            if (gjc < nc && gic < nc) rc[gjc * nc + gic] = sum * 0.25f;
        }
    }
}

static dim3 grd(int n, int tt) { int g = (n + tt - 1) / tt; return dim3(g, g); }

} // namespace

extern "C" void kernel_launch(void* const* d_in, const int* in_sizes, int n_in,
                              void* d_out, int out_size, void* d_ws, size_t ws_size,
                              hipStream_t stream) {
    (void)in_sizes; (void)n_in; (void)out_size; (void)ws_size;

    const float* cx0 = (const float*)d_in[1];
    const float* cy0 = (const float*)d_in[2];
    const float* cx1 = (const float*)d_in[4];
    const float* cy1 = (const float*)d_in[5];
    const float* cx2 = (const float*)d_in[7];
    const float* cy2 = (const float*)d_in[8];
    const float* cx3 = (const float*)d_in[10];
    const float* cy3 = (const float*)d_in[11];
    const float* rhs = (const float*)d_in[12];

    float* O = (float*)d_out;            // 2048^2 (also used as ping buffer)
    float* w = (float*)d_ws;
    float* W   = w; w += 2048 * 2048;
    float* rc1 = w; w += 1024 * 1024;
    float* a1  = w; w += 1024 * 1024;
    float* b1  = w; w += 1024 * 1024;
    float* rc2 = w; w += 512 * 512;
    float* a2  = w; w += 512 * 512;
    float* b2  = w; w += 512 * 512;
    float* rc3 = w; w += 256 * 256;
    float* a3  = w; w += 256 * 256;

    const dim3 blk(512, 1, 1);
    // TT: STEPS=2+RESTRICT->58; STEPS=4+RESTRICT->54; STEPS=2+PROLONG->60; L3 S=22->20.

    // ---------- cycle 1 ----------
    mg_fused<2, 64, 512, true, true, false><<<grd(2048, 58), blk, 0, stream>>>(
        nullptr, O, rhs, cx0, cy0, 1.0f, 2048, nullptr, rc1);
    mg_fused<2, 64, 512, true, true, false><<<grd(1024, 58), blk, 0, stream>>>(
        nullptr, a1, rc1, cx1, cy1, 0.25f, 1024, nullptr, rc2);
    mg_fused<2, 64, 512, true, true, false><<<grd(512, 58), blk, 0, stream>>>(
        nullptr, a2, rc2, cx2, cy2, 0.0625f, 512, nullptr, rc3);
    mg_fused<22, 64, 512, true, false, false><<<grd(256, 20), blk, 0, stream>>>(
        nullptr, a3, rc3, cx3, cy3, 0.015625f, 256, nullptr, nullptr);
    mg_fused<2, 64, 512, false, false, true><<<grd(512, 60), blk, 0, stream>>>(
        a2, b2, rc2, cx2, cy2, 0.0625f, 512, a3, nullptr);
    mg_fused<2, 64, 512, false, false, true><<<grd(1024, 60), blk, 0, stream>>>(
        a1, b1, rc1, cx1, cy1, 0.25f, 1024, b2, nullptr);
    // ---------- cross-cycle L0: prolong + post(2) + pre(2) + restrict ----------
    mg_fused<4, 64, 512, false, true, true><<<grd(2048, 54), blk, 0, stream>>>(
        O, W, rhs, cx0, cy0, 1.0f, 2048, b1, rc1);
    // ---------- cycle 2 ----------
    mg_fused<2, 64, 512, true, true, false><<<grd(1024, 58), blk, 0, stream>>>(
        nullptr, a1, rc1, cx1, cy1, 0.25f, 1024, nullptr, rc2);
    mg_fused<2, 64, 512, true, true, false><<<grd(512, 58), blk, 0, stream>>>(
        nullptr, a2, rc2, cx2, cy2, 0.0625f, 512, nullptr, rc3);
    mg_fused<22, 64, 512, true, false, false><<<grd(256, 20), blk, 0, stream>>>(
        nullptr, a3, rc3, cx3, cy3, 0.015625f, 256, nullptr, nullptr);
    mg_fused<2, 64, 512, false, false, true><<<grd(512, 60), blk, 0, stream>>>(
        a2, b2, rc2, cx2, cy2, 0.0625f, 512, a3, nullptr);
    mg_fused<2, 64, 512, false, false, true><<<grd(1024, 60), blk, 0, stream>>>(
        a1, b1, rc1, cx1, cy1, 0.25f, 1024, b2, nullptr);
    mg_fused<2, 64, 512, false, false, true><<<grd(2048, 60), blk, 0, stream>>>(
        W, O, rhs, cx0, cy0, 1.0f, 2048, b1, nullptr);
}

// Round 8
// 317.642 us; speedup vs baseline: 2.2110x; 1.0580x over previous
//
#include <hip/hip_runtime.h>

// Multigrid V-cycle: div(c grad u) - u = rhs, 5-pt stencil, fp32, mask==1.
// Register-strip + double-buffered LDS (ONE barrier per sweep).
// RG=32 region, BLK=256 (8 strips x 4 rows): 4x more blocks than RG=64,
// 8 barrier-groups/CU, VGPR<=64 -> 8 waves/SIMD.
// Block-uniform interior fast path: no per-point bounds checks, no 64-bit
// per-k address mul, prolong 4-tap unconditional with *0.0625f (==/16, exact).
// Validity: OOB loads are zero and stay finite; after s sweeps cells at
// depth>=s are exact; tile at depth>=H. cxw via __shfl_up (tx==0 lane:
// depth-0 column, outside validity ring).

namespace {

constexpr float OMEGA_C = 0.9f;

template<int STEPS, int RG, int BLK, bool U0, bool RESTRICT, bool PROLONG>
__global__ __launch_bounds__(BLK) void mg_fused(
    const float* __restrict__ uin, float* __restrict__ uout,
    const float* __restrict__ rhs,
    const float* __restrict__ cx, const float* __restrict__ cy,
    float inv_dx2, int n,
    const float* __restrict__ e,   // PROLONG: coarse error (n/2)^2
    float* __restrict__ rc)        // RESTRICT: coarse residual out (n/2)^2
{
    constexpr int H    = STEPS + (RESTRICT ? 1 : 0);
    constexpr int TT   = RG - 2 * H;
    constexpr int NS   = BLK / RG;
    constexpr int SR   = RG / NS;
    constexpr int SROW = RG + 2;          // pad cols 0 and RG+1 (zeroed)
    static_assert(TT > 0 && BLK % RG == 0 && RG % NS == 0, "geometry");
    static_assert(!RESTRICT || (TT % 2 == 0), "restrict needs even tile");

    __shared__ float sA[RG * SROW];
    __shared__ float sB[RG * SROW];

    const int tid = threadIdx.x;
    const int tx  = tid & (RG - 1);
    const int ty  = tid / RG;
    const int jb  = ty * SR;
    const int bx  = blockIdx.x * TT - H;
    const int by  = blockIdx.y * TT - H;
    const int gi  = bx + tx;
    const int nc  = n >> 1;
    const int gj0 = by + jb;

    float u[SR], rh[SR], sv[SR], cxs[SR], cxw[SR], cyn[SR];
    float cys0;

    // zero pad columns in both buffers
    if (tid < RG) {
        sA[tid * SROW] = 0.0f;  sA[tid * SROW + RG + 1] = 0.0f;
        sB[tid * SROW] = 0.0f;  sB[tid * SROW + RG + 1] = 0.0f;
    }

    // block-uniform interiority (covers u/cx/cy/rhs halo AND prolong ii/jj)
    const bool interior = (bx >= 2) && (by >= 2) &&
                          (bx + RG + 2 <= n) && (by + RG + 2 <= n);

    if (interior) {
        // ---------- fast path: predicate-free, single base ----------
        const size_t g0 = (size_t)gj0 * n + gi;
        cys0 = cy[g0 - n] * inv_dx2;
#pragma unroll
        for (int k = 0; k < SR; ++k) {
            const size_t g = g0 + (size_t)k * n;
            cxs[k] = cx[g] * inv_dx2;     // pow2 scale: exact
            cyn[k] = cy[g] * inv_dx2;
            rh[k]  = rhs[g];
            float vu;
            if constexpr (U0) vu = 0.0f; else vu = uin[g];
            if constexpr (PROLONG) {
                const int gj = gj0 + k;
                const int ic = gi >> 1, jc = gj >> 1;
                const int ii = ic + ((gi & 1) ? 1 : -1);
                const int jj = jc + ((gj & 1) ? 1 : -1);
                const float vc  = e[jc * nc + ic];
                const float vsi = e[jc * nc + ii];
                const float vsj = e[jj * nc + ic];
                const float vd  = e[jj * nc + ii];
                // d == 16 for interior: w/16 == w*0.0625f bit-exactly
                vu += (((9.0f * vc + 3.0f * vsi) + 3.0f * vsj) + vd) * 0.0625f;
            }
            u[k] = vu;
        }
    } else {
        // ---------- slow path: full bounds handling (boundary ring) ----------
        const bool gi_ok = (unsigned)gi < (unsigned)n;
        {
            const int gjm = gj0 - 1;
            const bool okm = gi_ok && ((unsigned)gjm < (unsigned)n);
            cys0 = okm ? cy[(size_t)gjm * n + gi] * inv_dx2 : 0.0f;
        }
#pragma unroll
        for (int k = 0; k < SR; ++k) {
            const int gj = gj0 + k;
            const bool ok = gi_ok && ((unsigned)gj < (unsigned)n);
            float vcx = 0.f, vcy = 0.f, vrh = 0.f, vu = 0.f;
            if (ok) {
                const size_t g = (size_t)gj * n + gi;
                vcx = cx[g] * inv_dx2;
                vcy = cy[g] * inv_dx2;
                vrh = rhs[g];
                if constexpr (!U0) vu = uin[g];
                if constexpr (PROLONG) {
                    const int ic = gi >> 1, jc = gj >> 1;
                    const int ii = ic + ((gi & 1) ? 1 : -1);
                    const int jj = jc + ((gj & 1) ? 1 : -1);
                    const bool iok = (unsigned)ii < (unsigned)nc;
                    const bool jok = (unsigned)jj < (unsigned)nc;
                    const float vc  = e[jc * nc + ic];
                    const float vsi = iok ? e[jc * nc + ii] : 0.0f;
                    const float vsj = jok ? e[jj * nc + ic] : 0.0f;
                    const float vd  = (iok && jok) ? e[jj * nc + ii] : 0.0f;
                    const float ws  = ((9.0f * vc + 3.0f * vsi) + 3.0f * vsj) + vd;
                    const float dn  = ((9.0f + (iok ? 3.0f : 0.0f)) + (jok ? 3.0f : 0.0f))
                                    + ((iok && jok) ? 1.0f : 0.0f);
                    vu += ws / dn;
                }
            }
            cxs[k] = vcx; cyn[k] = vcy; rh[k] = vrh; u[k] = vu;
        }
    }

    // cxw via lane shuffle within each RG-lane row group
#pragma unroll
    for (int k = 0; k < SR; ++k) cxw[k] = __shfl_up(cxs[k], 1, RG);

    // omega/diag hoisted (division ONCE)
#pragma unroll
    for (int k = 0; k < SR; ++k) {
        const float cys  = k ? cyn[k - 1] : cys0;
        const float diag = -((cxs[k] + cxw[k]) + (cyn[k] + cys)) - 1.0f;  // LAM=1
        const float inv  = (diag != 0.0f) ? 1.0f / diag : 0.0f;
        sv[k] = OMEGA_C * inv;
    }

    // seed buffer A with u
    {
        const int base = jb * SROW + 1 + tx;
#pragma unroll
        for (int k = 0; k < SR; ++k) sA[base + k * SROW] = u[k];
    }
    __syncthreads();

    // ---- fused sweeps, double-buffered: ONE barrier per sweep ----
    float* cur = sA;
    float* nxt = sB;
    for (int s = 0; s < STEPS; ++s) {
        const float us_edge = (jb > 0)       ? cur[(jb - 1)  * SROW + 1 + tx] : 0.0f;
        const float un_edge = (jb + SR < RG) ? cur[(jb + SR) * SROW + 1 + tx] : 0.0f;
        const int base = jb * SROW + 1 + tx;
        float prev_old = us_edge;
        const bool last = (s == STEPS - 1);
#pragma unroll
        for (int k = 0; k < SR; ++k) {
            const float um = u[k];
            const float ue = cur[base + k * SROW + 1];
            const float uw = cur[base + k * SROW - 1];
            const float un = (k < SR - 1) ? u[k + 1] : un_edge;
            const float us = prev_old;
            const float cys = k ? cyn[k - 1] : cys0;
            const float lx = cxs[k] * (ue - um) - cxw[k] * (um - uw);
            const float ly = cyn[k] * (un - um) - cys    * (um - us);
            const float r  = rh[k] - ((lx + ly) - um);
            prev_old = um;
            u[k] = um + sv[k] * r;
        }
        if (last && !RESTRICT) break;          // neighbors not needed again
#pragma unroll
        for (int k = 0; k < SR; ++k) nxt[base + k * SROW] = u[k];
        __syncthreads();
        float* t = cur; cur = nxt; nxt = t;
    }

    // ---- store smoothed tile (depth >= H fully valid) ----
#pragma unroll
    for (int k = 0; k < SR; ++k) {
        const int lr = jb + k;
        const int gj = by + lr;
        if (lr >= H && lr < H + TT && tx >= H && tx < H + TT &&
            (interior || (gj < n && gi < n))) {
            uout[(size_t)gj * n + gi] = u[k];
        }
    }

    // ---- fused residual + full-weighting restriction ----
    if constexpr (RESTRICT) {
        // post-sweep u is in `cur` (last sweep wrote + swapped). Residual from it.
        float res[SR];
        const float us_edge = (jb > 0)       ? cur[(jb - 1)  * SROW + 1 + tx] : 0.0f;
        const float un_edge = (jb + SR < RG) ? cur[(jb + SR) * SROW + 1 + tx] : 0.0f;
        const int base = jb * SROW + 1 + tx;
        float prev_old = us_edge;
#pragma unroll
        for (int k = 0; k < SR; ++k) {
            const float um = u[k];
            const float ue = cur[base + k * SROW + 1];
            const float uw = cur[base + k * SROW - 1];
            const float un = (k < SR - 1) ? u[k + 1] : un_edge;
            const float us = prev_old;
            const float cys = k ? cyn[k - 1] : cys0;
            const float lx = cxs[k] * (ue - um) - cxw[k] * (um - uw);
            const float ly = cyn[k] * (un - um) - cys    * (um - us);
            res[k] = rh[k] - ((lx + ly) - um);
            prev_old = um;
        }
        __syncthreads();   // all reads of cur done before overwriting nxt
#pragma unroll
        for (int k = 0; k < SR; ++k) nxt[base + k * SROW] = res[k];
        __syncthreads();

        constexpr int TC = TT / 2;
        for (int t = tid; t < TC * TC; t += BLK) {
            const int tj = t / TC, ti = t - tj * TC;    // TC constexpr -> magic mul
            const int a = (H + 2 * tj) * SROW + 1 + (H + 2 * ti);
            const float sum = ((nxt[a] + nxt[a + SROW]) + nxt[a + 1]) + nxt[a + SROW + 1];
            const int gjc = blockIdx.y * TC + tj;
            const int gic = blockIdx.x * TC + ti;
            if (gjc < nc && gic < nc) rc[gjc * nc + gic] = sum * 0.25f;
        }
    }
}

static dim3 grd(int n, int tt) { int g = (n + tt - 1) / tt; return dim3(g, g); }

} // namespace

extern "C" void kernel_launch(void* const* d_in, const int* in_sizes, int n_in,
                              void* d_out, int out_size, void* d_ws, size_t ws_size,
                              hipStream_t stream) {
    (void)in_sizes; (void)n_in; (void)out_size; (void)ws_size;

    const float* cx0 = (const float*)d_in[1];
    const float* cy0 = (const float*)d_in[2];
    const float* cx1 = (const float*)d_in[4];
    const float* cy1 = (const float*)d_in[5];
    const float* cx2 = (const float*)d_in[7];
    const float* cy2 = (const float*)d_in[8];
    const float* cx3 = (const float*)d_in[10];
    const float* cy3 = (const float*)d_in[11];
    const float* rhs = (const float*)d_in[12];

    float* O = (float*)d_out;            // 2048^2 (also used as ping buffer)
    float* w = (float*)d_ws;
    float* W   = w; w += 2048 * 2048;
    float* rc1 = w; w += 1024 * 1024;
    float* a1  = w; w += 1024 * 1024;
    float* b1  = w; w += 1024 * 1024;
    float* rc2 = w; w += 512 * 512;
    float* a2  = w; w += 512 * 512;
    float* b2  = w; w += 512 * 512;
    float* rc3 = w; w += 256 * 256;
    float* a3  = w; w += 256 * 256;
    float* b3  = w; w += 256 * 256;

    const dim3 blk(256, 1, 1);
    // TT: S2+R -> 26; S4+R (X) -> 22; S2+P -> 28; L3 S11 -> 10.

    // ---------- cycle 1 ----------
    mg_fused<2, 32, 256, true, true, false><<<grd(2048, 26), blk, 0, stream>>>(
        nullptr, O, rhs, cx0, cy0, 1.0f, 2048, nullptr, rc1);
    mg_fused<2, 32, 256, true, true, false><<<grd(1024, 26), blk, 0, stream>>>(
        nullptr, a1, rc1, cx1, cy1, 0.25f, 1024, nullptr, rc2);
    mg_fused<2, 32, 256, true, true, false><<<grd(512, 26), blk, 0, stream>>>(
        nullptr, a2, rc2, cx2, cy2, 0.0625f, 512, nullptr, rc3);
    // coarsest: 22 sweeps = 11 + 11 (676 blocks each)
    mg_fused<11, 32, 256, true,  false, false><<<grd(256, 10), blk, 0, stream>>>(
        nullptr, a3, rc3, cx3, cy3, 0.015625f, 256, nullptr, nullptr);
    mg_fused<11, 32, 256, false, false, false><<<grd(256, 10), blk, 0, stream>>>(
        a3, b3, rc3, cx3, cy3, 0.015625f, 256, nullptr, nullptr);
    mg_fused<2, 32, 256, false, false, true><<<grd(512, 28), blk, 0, stream>>>(
        a2, b2, rc2, cx2, cy2, 0.0625f, 512, b3, nullptr);
    mg_fused<2, 32, 256, false, false, true><<<grd(1024, 28), blk, 0, stream>>>(
        a1, b1, rc1, cx1, cy1, 0.25f, 1024, b2, nullptr);
    // ---------- cross-cycle L0: prolong + post(2) + pre(2) + restrict ----------
    mg_fused<4, 32, 256, false, true, true><<<grd(2048, 22), blk, 0, stream>>>(
        O, W, rhs, cx0, cy0, 1.0f, 2048, b1, rc1);
    // ---------- cycle 2 ----------
    mg_fused<2, 32, 256, true, true, false><<<grd(1024, 26), blk, 0, stream>>>(
        nullptr, a1, rc1, cx1, cy1, 0.25f, 1024, nullptr, rc2);
    mg_fused<2, 32, 256, true, true, false><<<grd(512, 26), blk, 0, stream>>>(
        nullptr, a2, rc2, cx2, cy2, 0.0625f, 512, nullptr, rc3);
    mg_fused<11, 32, 256, true,  false, false><<<grd(256, 10), blk, 0, stream>>>(
        nullptr, a3, rc3, cx3, cy3, 0.015625f, 256, nullptr, nullptr);
    mg_fused<11, 32, 256, false, false, false><<<grd(256, 10), blk, 0, stream>>>(
        a3, b3, rc3, cx3, cy3, 0.015625f, 256, nullptr, nullptr);
    mg_fused<2, 32, 256, false, false, true><<<grd(512, 28), blk, 0, stream>>>(
        a2, b2, rc2, cx2, cy2, 0.0625f, 512, b3, nullptr);
    mg_fused<2, 32, 256, false, false, true><<<grd(1024, 28), blk, 0, stream>>>(
        a1, b1, rc1, cx1, cy1, 0.25f, 1024, b2, nullptr);
    mg_fused<2, 32, 256, false, false, true><<<grd(2048, 28), blk, 0, stream>>>(
        W, O, rhs, cx0, cy0, 1.0f, 2048, b1, nullptr);
}

// Round 9
// 262.615 us; speedup vs baseline: 2.6742x; 1.2095x over previous
//
#include <hip/hip_runtime.h>

// Multigrid V-cycle: div(c grad u) - u = rhs, 5-pt stencil, fp32, mask==1.
// Register-strip + double-buffered LDS (ONE barrier per sweep).
// Rectangular regions: RGX x RGY, BLK=256 (NSY strips of SR rows).
//   n=2048 kernels: 64x32 (halo ratio X: 1.72 vs 2.12 at 32x32)
//   n<=1024 kernels: 32x32 (more blocks; data is L2-resident anyway)
// 1D grid + XCD-aware bijective swizzle (m204): blocks with bid%8==xcd get a
// contiguous row-major tile chunk -> halo re-reads hit that XCD's L2.
// Block-uniform interior fast path; OOB-zero => no bounds checks in sweeps;
// ring validity: depth>=s exact after s sweeps; tile at depth>=H.

namespace {

constexpr float OMEGA_C = 0.9f;

template<int STEPS, int RGX, int RGY, bool U0, bool RESTRICT, bool PROLONG>
__global__ __launch_bounds__(256) void mg_fused(
    const float* __restrict__ uin, float* __restrict__ uout,
    const float* __restrict__ rhs,
    const float* __restrict__ cx, const float* __restrict__ cy,
    float inv_dx2, int n, int gx,
    const float* __restrict__ e,   // PROLONG: coarse error (n/2)^2
    float* __restrict__ rc)        // RESTRICT: coarse residual out (n/2)^2
{
    constexpr int BLK  = 256;
    constexpr int H    = STEPS + (RESTRICT ? 1 : 0);
    constexpr int TTX  = RGX - 2 * H;
    constexpr int TTY  = RGY - 2 * H;
    constexpr int NSY  = BLK / RGX;       // strips per region
    constexpr int SR   = RGY / NSY;       // rows per strip
    constexpr int SROW = RGX + 2;         // pad cols 0 and RGX+1 (zeroed)
    static_assert(TTX > 0 && TTY > 0 && BLK % RGX == 0 && RGY % NSY == 0, "geometry");
    static_assert(!RESTRICT || (TTX % 2 == 0 && TTY % 2 == 0), "restrict tile even");

    __shared__ float sA[RGY * SROW];
    __shared__ float sB[RGY * SROW];

    // ---- XCD-aware bijective tile swizzle (bid%8 -> contiguous chunk) ----
    const int nwg  = gridDim.x;
    const int bid  = blockIdx.x;
    const int q    = nwg >> 3, r = nwg & 7;
    const int xcd  = bid & 7;
    const int wgid = (xcd < r ? xcd * (q + 1) : r * (q + 1) + (xcd - r) * q) + (bid >> 3);
    const int tiley = wgid / gx;
    const int tilex = wgid - tiley * gx;

    const int tid = threadIdx.x;
    const int tx  = tid & (RGX - 1);
    const int ty  = tid / RGX;
    const int jb  = ty * SR;
    const int bx  = tilex * TTX - H;
    const int by  = tiley * TTY - H;
    const int gi  = bx + tx;
    const int nc  = n >> 1;
    const int gj0 = by + jb;

    float u[SR], rh[SR], sv[SR], cxs[SR], cxw[SR], cyn[SR];
    float cys0;

    // zero pad columns in both buffers
    if (tid < RGY) {
        sA[tid * SROW] = 0.0f;  sA[tid * SROW + RGX + 1] = 0.0f;
        sB[tid * SROW] = 0.0f;  sB[tid * SROW + RGX + 1] = 0.0f;
    }

    // block-uniform interiority (covers stencil halo AND prolong ii/jj range)
    const bool interior = (bx >= 2) && (by >= 2) &&
                          (bx + RGX + 2 <= n) && (by + RGY + 2 <= n);

    if (interior) {
        // ---------- fast path: predicate-free, single base ----------
        const size_t g0 = (size_t)gj0 * n + gi;
        cys0 = cy[g0 - n] * inv_dx2;
#pragma unroll
        for (int k = 0; k < SR; ++k) {
            const size_t g = g0 + (size_t)k * n;
            cxs[k] = cx[g] * inv_dx2;     // pow2 scale: exact
            cyn[k] = cy[g] * inv_dx2;
            rh[k]  = rhs[g];
            float vu;
            if constexpr (U0) vu = 0.0f; else vu = uin[g];
            if constexpr (PROLONG) {
                const int gj = gj0 + k;
                const int ic = gi >> 1, jc = gj >> 1;
                const int ii = ic + ((gi & 1) ? 1 : -1);
                const int jj = jc + ((gj & 1) ? 1 : -1);
                const float vc  = e[jc * nc + ic];
                const float vsi = e[jc * nc + ii];
                const float vsj = e[jj * nc + ic];
                const float vd  = e[jj * nc + ii];
                // d == 16 for interior: w/16 == w*0.0625f bit-exactly
                vu += (((9.0f * vc + 3.0f * vsi) + 3.0f * vsj) + vd) * 0.0625f;
            }
            u[k] = vu;
        }
    } else {
        // ---------- slow path: full bounds handling (boundary ring) ----------
        const bool gi_ok = (unsigned)gi < (unsigned)n;
        {
            const int gjm = gj0 - 1;
            const bool okm = gi_ok && ((unsigned)gjm < (unsigned)n);
            cys0 = okm ? cy[(size_t)gjm * n + gi] * inv_dx2 : 0.0f;
        }
#pragma unroll
        for (int k = 0; k < SR; ++k) {
            const int gj = gj0 + k;
            const bool ok = gi_ok && ((unsigned)gj < (unsigned)n);
            float vcx = 0.f, vcy = 0.f, vrh = 0.f, vu = 0.f;
            if (ok) {
                const size_t g = (size_t)gj * n + gi;
                vcx = cx[g] * inv_dx2;
                vcy = cy[g] * inv_dx2;
                vrh = rhs[g];
                if constexpr (!U0) vu = uin[g];
                if constexpr (PROLONG) {
                    const int ic = gi >> 1, jc = gj >> 1;
                    const int ii = ic + ((gi & 1) ? 1 : -1);
                    const int jj = jc + ((gj & 1) ? 1 : -1);
                    const bool iok = (unsigned)ii < (unsigned)nc;
                    const bool jok = (unsigned)jj < (unsigned)nc;
                    const float vc  = e[jc * nc + ic];
                    const float vsi = iok ? e[jc * nc + ii] : 0.0f;
                    const float vsj = jok ? e[jj * nc + ic] : 0.0f;
                    const float vd  = (iok && jok) ? e[jj * nc + ii] : 0.0f;
                    const float ws  = ((9.0f * vc + 3.0f * vsi) + 3.0f * vsj) + vd;
                    const float dn  = ((9.0f + (iok ? 3.0f : 0.0f)) + (jok ? 3.0f : 0.0f))
                                    + ((iok && jok) ? 1.0f : 0.0f);
                    vu += ws / dn;
                }
            }
            cxs[k] = vcx; cyn[k] = vcy; rh[k] = vrh; u[k] = vu;
        }
    }

    // cxw via lane shuffle within each RGX-lane row group
#pragma unroll
    for (int k = 0; k < SR; ++k) cxw[k] = __shfl_up(cxs[k], 1, RGX);

    // omega/diag hoisted (division ONCE)
#pragma unroll
    for (int k = 0; k < SR; ++k) {
        const float cys  = k ? cyn[k - 1] : cys0;
        const float diag = -((cxs[k] + cxw[k]) + (cyn[k] + cys)) - 1.0f;  // LAM=1
        const float inv  = (diag != 0.0f) ? 1.0f / diag : 0.0f;
        sv[k] = OMEGA_C * inv;
    }

    // seed buffer A with u
    {
        const int base = jb * SROW + 1 + tx;
#pragma unroll
        for (int k = 0; k < SR; ++k) sA[base + k * SROW] = u[k];
    }
    __syncthreads();

    // ---- fused sweeps, double-buffered: ONE barrier per sweep ----
    float* cur = sA;
    float* nxt = sB;
    for (int s = 0; s < STEPS; ++s) {
        const float us_edge = (jb > 0)        ? cur[(jb - 1)  * SROW + 1 + tx] : 0.0f;
        const float un_edge = (jb + SR < RGY) ? cur[(jb + SR) * SROW + 1 + tx] : 0.0f;
        const int base = jb * SROW + 1 + tx;
        float prev_old = us_edge;
        const bool last = (s == STEPS - 1);
#pragma unroll
        for (int k = 0; k < SR; ++k) {
            const float um = u[k];
            const float ue = cur[base + k * SROW + 1];
            const float uw = cur[base + k * SROW - 1];
            const float un = (k < SR - 1) ? u[k + 1] : un_edge;
            const float us = prev_old;
            const float cys = k ? cyn[k - 1] : cys0;
            const float lx = cxs[k] * (ue - um) - cxw[k] * (um - uw);
            const float ly = cyn[k] * (un - um) - cys    * (um - us);
            const float r  = rh[k] - ((lx + ly) - um);
            prev_old = um;
            u[k] = um + sv[k] * r;
        }
        if (last && !RESTRICT) break;          // neighbors not needed again
#pragma unroll
        for (int k = 0; k < SR; ++k) nxt[base + k * SROW] = u[k];
        __syncthreads();
        float* t = cur; cur = nxt; nxt = t;
    }

    // ---- store smoothed tile (depth >= H fully valid) ----
#pragma unroll
    for (int k = 0; k < SR; ++k) {
        const int lr = jb + k;
        const int gj = by + lr;
        if (lr >= H && lr < H + TTY && tx >= H && tx < H + TTX &&
            (interior || (gj < n && gi < n))) {
            uout[(size_t)gj * n + gi] = u[k];
        }
    }

    // ---- fused residual + full-weighting restriction ----
    if constexpr (RESTRICT) {
        // post-sweep u is in `cur` (last sweep wrote + swapped). Residual from it.
        float res[SR];
        const float us_edge = (jb > 0)        ? cur[(jb - 1)  * SROW + 1 + tx] : 0.0f;
        const float un_edge = (jb + SR < RGY) ? cur[(jb + SR) * SROW + 1 + tx] : 0.0f;
        const int base = jb * SROW + 1 + tx;
        float prev_old = us_edge;
#pragma unroll
        for (int k = 0; k < SR; ++k) {
            const float um = u[k];
            const float ue = cur[base + k * SROW + 1];
            const float uw = cur[base + k * SROW - 1];
            const float un = (k < SR - 1) ? u[k + 1] : un_edge;
            const float us = prev_old;
            const float cys = k ? cyn[k - 1] : cys0;
            const float lx = cxs[k] * (ue - um) - cxw[k] * (um - uw);
            const float ly = cyn[k] * (un - um) - cys    * (um - us);
            res[k] = rh[k] - ((lx + ly) - um);
            prev_old = um;
        }
        __syncthreads();   // all reads of cur done before overwriting nxt
#pragma unroll
        for (int k = 0; k < SR; ++k) nxt[base + k * SROW] = res[k];
        __syncthreads();

        constexpr int TCX = TTX / 2;
        constexpr int TCY = TTY / 2;
        for (int t = tid; t < TCX * TCY; t += BLK) {
            const int tj = t / TCX, ti = t - tj * TCX;   // constexpr -> magic mul
            const int a = (H + 2 * tj) * SROW + 1 + (H + 2 * ti);
            const float sum = ((nxt[a] + nxt[a + SROW]) + nxt[a + 1]) + nxt[a + SROW + 1];
            const int gjc = tiley * TCY + tj;
            const int gic = tilex * TCX + ti;
            if (gjc < nc && gic < nc) rc[gjc * nc + gic] = sum * 0.25f;
        }
    }
}

static inline int cdiv(int a, int b) { return (a + b - 1) / b; }

} // namespace

extern "C" void kernel_launch(void* const* d_in, const int* in_sizes, int n_in,
                              void* d_out, int out_size, void* d_ws, size_t ws_size,
                              hipStream_t stream) {
    (void)in_sizes; (void)n_in; (void)out_size; (void)ws_size;

    const float* cx0 = (const float*)d_in[1];
    const float* cy0 = (const float*)d_in[2];
    const float* cx1 = (const float*)d_in[4];
    const float* cy1 = (const float*)d_in[5];
    const float* cx2 = (const float*)d_in[7];
    const float* cy2 = (const float*)d_in[8];
    const float* cx3 = (const float*)d_in[10];
    const float* cy3 = (const float*)d_in[11];
    const float* rhs = (const float*)d_in[12];

    float* O = (float*)d_out;            // 2048^2 (also used as ping buffer)
    float* w = (float*)d_ws;
    float* W   = w; w += 2048 * 2048;
    float* rc1 = w; w += 1024 * 1024;
    float* a1  = w; w += 1024 * 1024;
    float* b1  = w; w += 1024 * 1024;
    float* rc2 = w; w += 512 * 512;
    float* a2  = w; w += 512 * 512;
    float* b2  = w; w += 512 * 512;
    float* rc3 = w; w += 256 * 256;
    float* a3  = w; w += 256 * 256;
    float* b3  = w; w += 256 * 256;

    const dim3 blk(256, 1, 1);

    // L0 (n=2048): RGX=64, RGY=32.  TT: S2+R 58x26 | S4+R+P (X) 54x22 | S2+P 60x28
    const int gxA0 = cdiv(2048, 58), gyA0 = cdiv(2048, 26);
    const int gxX  = cdiv(2048, 54), gyX  = cdiv(2048, 22);
    const int gxB0 = cdiv(2048, 60), gyB0 = cdiv(2048, 28);
    // L1 (n=1024), L2 (n=512): RG 32x32.  TT: S2+R 26 | S2+P 28
    const int gxA1 = cdiv(1024, 26), gxB1 = cdiv(1024, 28);
    const int gxA2 = cdiv(512, 26),  gxB2 = cdiv(512, 28);
    // L3 (n=256): RG 32x32, S11 -> TT 10
    const int gxC  = cdiv(256, 10);

    for (int c = 0; c < 2; ++c) {
        if (c == 0) {
            // cycle-1 L0 pre-smooth + restrict
            mg_fused<2, 64, 32, true, true, false><<<dim3(gxA0 * gyA0), blk, 0, stream>>>(
                nullptr, O, rhs, cx0, cy0, 1.0f, 2048, gxA0, nullptr, rc1);
        } else {
            // cross-cycle L0: prolong + post(2) + pre(2) + restrict
            mg_fused<4, 64, 32, false, true, true><<<dim3(gxX * gyX), blk, 0, stream>>>(
                O, W, rhs, cx0, cy0, 1.0f, 2048, gxX, b1, rc1);
        }
        mg_fused<2, 32, 32, true, true, false><<<dim3(gxA1 * gxA1), blk, 0, stream>>>(
            nullptr, a1, rc1, cx1, cy1, 0.25f, 1024, gxA1, nullptr, rc2);
        mg_fused<2, 32, 32, true, true, false><<<dim3(gxA2 * gxA2), blk, 0, stream>>>(
            nullptr, a2, rc2, cx2, cy2, 0.0625f, 512, gxA2, nullptr, rc3);
        // coarsest: 22 sweeps = 11 + 11 (676 blocks each)
        mg_fused<11, 32, 32, true,  false, false><<<dim3(gxC * gxC), blk, 0, stream>>>(
            nullptr, a3, rc3, cx3, cy3, 0.015625f, 256, gxC, nullptr, nullptr);
        mg_fused<11, 32, 32, false, false, false><<<dim3(gxC * gxC), blk, 0, stream>>>(
            a3, b3, rc3, cx3, cy3, 0.015625f, 256, gxC, nullptr, nullptr);
        mg_fused<2, 32, 32, false, false, true><<<dim3(gxB2 * gxB2), blk, 0, stream>>>(
            a2, b2, rc2, cx2, cy2, 0.0625f, 512, gxB2, b3, nullptr);
        mg_fused<2, 32, 32, false, false, true><<<dim3(gxB1 * gxB1), blk, 0, stream>>>(
            a1, b1, rc1, cx1, cy1, 0.25f, 1024, gxB1, b2, nullptr);
    }
    // final L0: prolong + post-smooth(2): W -> O
    mg_fused<2, 64, 32, false, false, true><<<dim3(gxB0 * gyB0), blk, 0, stream>>>(
        W, O, rhs, cx0, cy0, 1.0f, 2048, gxB0, b1, nullptr);
}